// Round 9
// baseline (234.192 us; speedup 1.0000x reference)
//
#include <hip/hip_runtime.h>
#include <math.h>

#define IN_C 128
#define HID_C 64
#define OUT_C 40

typedef unsigned short u16;

__device__ __forceinline__ float readlane_f(float v, int l) {
  return __uint_as_float(__builtin_amdgcn_readlane(__float_as_uint(v), l));
}
__device__ __forceinline__ float bf2f(u16 u) {
  return __uint_as_float(((unsigned int)u) << 16);
}
__device__ __forceinline__ u16 f2bf(float f) {
  unsigned int u = __float_as_uint(f);
  u += 0x7fffu + ((u >> 16) & 1u);   // round to nearest even
  return (u16)(u >> 16);
}

// ---- grid-stride int4 zero ----
__global__ void zero4_kernel(int4* __restrict__ p, long long n4) {
  long long i = (long long)blockIdx.x * blockDim.x + threadIdx.x;
  long long stride = (long long)gridDim.x * blockDim.x;
  for (; i < n4; i += stride) p[i] = make_int4(0, 0, 0, 0);
}

// ---- degree: count incoming edges (dst side), int atomics ----
__global__ void deg_kernel(const int* __restrict__ dst, int E,
                           int* __restrict__ deg) {
  int i = blockIdx.x * blockDim.x + threadIdx.x;
  int stride = gridDim.x * blockDim.x;
  for (int e = i; e < E; e += stride) atomicAdd(&deg[dst[e]], 1);
}

// ---- scan stage 1: per-1024-chunk inclusive scan + chunk totals ----
__global__ __launch_bounds__(256) void scan1_kernel(
    const int* __restrict__ deg, int* __restrict__ S, int* __restrict__ BS,
    int n) {
  __shared__ int sums[256];
  int t = threadIdx.x;
  int i0 = blockIdx.x * 1024 + t * 4;
  int v0 = (i0 + 0 < n) ? deg[i0 + 0] : 0;
  int v1 = (i0 + 1 < n) ? deg[i0 + 1] : 0;
  int v2 = (i0 + 2 < n) ? deg[i0 + 2] : 0;
  int v3 = (i0 + 3 < n) ? deg[i0 + 3] : 0;
  v1 += v0; v2 += v1; v3 += v2;
  sums[t] = v3;
  __syncthreads();
  for (int off = 1; off < 256; off <<= 1) {
    int x = (t >= off) ? sums[t - off] : 0;
    __syncthreads();
    sums[t] += x;
    __syncthreads();
  }
  int excl = t ? sums[t - 1] : 0;
  if (i0 + 0 < n) S[i0 + 0] = v0 + excl;
  if (i0 + 1 < n) S[i0 + 1] = v1 + excl;
  if (i0 + 2 < n) S[i0 + 2] = v2 + excl;
  if (i0 + 3 < n) S[i0 + 3] = v3 + excl;
  if (t == 255) BS[blockIdx.x] = sums[255];
}

// ---- scan stage 2: exclusive scan of chunk totals (nb <= 128) ----
__global__ __launch_bounds__(128) void scan2_kernel(int* __restrict__ BS,
                                                    int nb) {
  __shared__ int s[128];
  int t = threadIdx.x;
  s[t] = (t < nb) ? BS[t] : 0;
  __syncthreads();
  for (int off = 1; off < 128; off <<= 1) {
    int x = (t >= off) ? s[t - off] : 0;
    __syncthreads();
    s[t] += x;
    __syncthreads();
  }
  if (t < nb) BS[t] = t ? s[t - 1] : 0;
}

// ---- scan stage 3: rowptr + cursor + dinv ----
__global__ void scan3_kernel(const int* __restrict__ S,
                             const int* __restrict__ BS,
                             const int* __restrict__ deg,
                             int* __restrict__ rowptr,
                             int* __restrict__ cursor,
                             float* __restrict__ dinv, int n) {
  int i = blockIdx.x * blockDim.x + threadIdx.x;
  if (i < n) {
    int d = deg[i];
    int r = S[i] + BS[i >> 10];      // inclusive prefix = rowptr[i+1]
    rowptr[i + 1] = r;
    cursor[i] = r - d;               // = rowptr[i]
    dinv[i] = rsqrtf((float)d + 1.0f);
    if (i == 0) rowptr[0] = 0;
  }
}

// ---- CSR fill: bucket src indices by dst ----
__global__ void fill_kernel(const int* __restrict__ eidx, int E,
                            int* __restrict__ cursor, int* __restrict__ csr) {
  int i = blockIdx.x * blockDim.x + threadIdx.x;
  int stride = gridDim.x * blockDim.x;
  for (int e = i; e < E; e += stride) {
    int s = eidx[e];
    int d = eidx[E + e];
    int pos = atomicAdd(&cursor[d], 1);
    csr[pos] = s;
  }
}

// ---- y' = bf16( dinv * (x @ W1) ): 64x64 tile, K chunked by 64 ----
#define XS_LD 68   // 64 + 4: float4-aligned, banks spread
__global__ __launch_bounds__(256) void gemm1_kernel(
    const float* __restrict__ x, const float* __restrict__ W1,
    const float* __restrict__ dinv, u16* __restrict__ y, int n) {
  __shared__ float xs[64 * XS_LD];    // 17.4 KiB
  __shared__ float wsh[64 * HID_C];   // 16 KiB, [k][j]
  int t = threadIdx.x;
  int rowBase = blockIdx.x * 64;
  const float4* xf4 = (const float4*)x;
  const float4* wf4 = (const float4*)W1;
  int tx = t & 15, ty = t >> 4;
  int i0 = ty * 4, j0 = tx * 4;
  float acc[4][4];
#pragma unroll
  for (int r = 0; r < 4; ++r)
#pragma unroll
    for (int j = 0; j < 4; ++j) acc[r][j] = 0.f;

  for (int kc = 0; kc < 2; ++kc) {           // K chunks of 64
#pragma unroll
    for (int k = 0; k < 4; ++k) {
      int t4 = t + k * 256;                  // 0..1023
      int row = t4 >> 4, c4 = t4 & 15;
      int gr = rowBase + row;
      if (gr >= n) gr = n - 1;
      *(float4*)&xs[row * XS_LD + c4 * 4] = xf4[(size_t)gr * 32 + kc * 16 + c4];
      *(float4*)&wsh[row * HID_C + c4 * 4] = wf4[(size_t)(kc * 64 + row) * 16 + c4];
    }
    __syncthreads();
#pragma unroll 2
    for (int c4 = 0; c4 < 64; c4 += 4) {
      float4 xv[4], wv[4];
#pragma unroll
      for (int r = 0; r < 4; ++r)
        xv[r] = *(const float4*)&xs[(i0 + r) * XS_LD + c4];
#pragma unroll
      for (int cc = 0; cc < 4; ++cc)
        wv[cc] = *(const float4*)&wsh[(c4 + cc) * HID_C + j0];
#pragma unroll
      for (int r = 0; r < 4; ++r) {
#pragma unroll
        for (int cc = 0; cc < 4; ++cc) {
          float xr = (&xv[r].x)[cc];
          acc[r][0] = fmaf(xr, wv[cc].x, acc[r][0]);
          acc[r][1] = fmaf(xr, wv[cc].y, acc[r][1]);
          acc[r][2] = fmaf(xr, wv[cc].z, acc[r][2]);
          acc[r][3] = fmaf(xr, wv[cc].w, acc[r][3]);
        }
      }
    }
    __syncthreads();
  }
#pragma unroll
  for (int r = 0; r < 4; ++r) {
    int i = rowBase + i0 + r;
    if (i < n) {
      float di = dinv[i];
      ushort4 v;
      v.x = f2bf(di * acc[r][0]);
      v.y = f2bf(di * acc[r][1]);
      v.z = f2bf(di * acc[r][2]);
      v.w = f2bf(di * acc[r][3]);
      *(ushort4*)&y[(size_t)i * HID_C + j0] = v;
    }
  }
}

// ---- gather(y' bf16) + bias/ReLU + fused z' = bf16(dinv * (h @ W2)) ----
// wave = node; 4 groups of 16 lanes, each takes every 4th edge, ushort4 ch
__global__ __launch_bounds__(256) void gather_gemm2_kernel(
    const ushort4* __restrict__ y4, const int* __restrict__ rowptr,
    const int* __restrict__ csr, const float* __restrict__ dinv,
    const float* __restrict__ b1, const float* __restrict__ W2,
    u16* __restrict__ z, int n) {
  int lane = threadIdx.x & 63;
  int grp = lane >> 4;             // 0..3: edge sub-group
  int q = lane & 15;               // channel quad (4q..4q+3)
  bool actj = lane < OUT_C;
  float w2[HID_C];
#pragma unroll
  for (int c = 0; c < HID_C; ++c) w2[c] = actj ? W2[c * OUT_C + lane] : 0.f;
  float4 b1v = ((const float4*)b1)[q];
  int wid = (int)((blockIdx.x * blockDim.x + threadIdx.x) >> 6);
  int nw = (int)((gridDim.x * blockDim.x) >> 6);
  for (int ii = wid; ii < n; ii += nw) {
    int i = __builtin_amdgcn_readfirstlane(ii);
    float4 acc = make_float4(0.f, 0.f, 0.f, 0.f);
    if (grp == 0) {
      ushort4 u = y4[(size_t)i * 16 + q];          // self term y'[i]
      acc.x = bf2f(u.x); acc.y = bf2f(u.y); acc.z = bf2f(u.z); acc.w = bf2f(u.w);
    }
    int e = rowptr[i] + grp, end = rowptr[i + 1];
    for (; e + 4 < end; e += 8) {
      int s0 = csr[e], s1 = csr[e + 4];
      ushort4 u0 = y4[(size_t)s0 * 16 + q];
      ushort4 u1 = y4[(size_t)s1 * 16 + q];
      acc.x += bf2f(u0.x) + bf2f(u1.x);
      acc.y += bf2f(u0.y) + bf2f(u1.y);
      acc.z += bf2f(u0.z) + bf2f(u1.z);
      acc.w += bf2f(u0.w) + bf2f(u1.w);
    }
    for (; e < end; e += 4) {
      int s = csr[e];
      ushort4 u = y4[(size_t)s * 16 + q];
      acc.x += bf2f(u.x); acc.y += bf2f(u.y);
      acc.z += bf2f(u.z); acc.w += bf2f(u.w);
    }
    // combine groups (xor 16, xor 32)
    acc.x += __shfl_xor(acc.x, 16); acc.y += __shfl_xor(acc.y, 16);
    acc.z += __shfl_xor(acc.z, 16); acc.w += __shfl_xor(acc.w, 16);
    acc.x += __shfl_xor(acc.x, 32); acc.y += __shfl_xor(acc.y, 32);
    acc.z += __shfl_xor(acc.z, 32); acc.w += __shfl_xor(acc.w, 32);
    float di = dinv[i];
    float4 hv;
    hv.x = fmaf(di, acc.x, b1v.x); hv.x = hv.x > 0.f ? hv.x : 0.f;
    hv.y = fmaf(di, acc.y, b1v.y); hv.y = hv.y > 0.f ? hv.y : 0.f;
    hv.z = fmaf(di, acc.z, b1v.z); hv.z = hv.z > 0.f ? hv.z : 0.f;
    hv.w = fmaf(di, acc.w, b1v.w); hv.w = hv.w > 0.f ? hv.w : 0.f;
    // z = h @ W2 via readlane broadcast (all lanes hold identical hv per q)
    float z0 = 0.f, z1 = 0.f;
#pragma unroll
    for (int p = 0; p < 16; ++p) {
      z0 = fmaf(readlane_f(hv.x, p), w2[4 * p + 0], z0);
      z1 = fmaf(readlane_f(hv.y, p), w2[4 * p + 1], z1);
      z0 = fmaf(readlane_f(hv.z, p), w2[4 * p + 2], z0);
      z1 = fmaf(readlane_f(hv.w, p), w2[4 * p + 3], z1);
    }
    if (actj) z[(size_t)i * OUT_C + lane] = f2bf(di * (z0 + z1));
  }
}

// ---- gather(z' bf16) + bias + log-softmax: 4 groups, q<10 active ----
__global__ __launch_bounds__(256) void gather40_kernel(
    const ushort4* __restrict__ z4, const int* __restrict__ rowptr,
    const int* __restrict__ csr, const float* __restrict__ dinv,
    const float* __restrict__ b2, float* __restrict__ out, int n) {
  int lane = threadIdx.x & 63;
  int grp = lane >> 4;             // 0..3: edge sub-group
  int q = lane & 15;               // channel quad; active q<10 (40 ch)
  bool act = q < 10;
  float4 b2v = ((const float4*)b2)[act ? q : 0];
  int wid = (int)((blockIdx.x * blockDim.x + threadIdx.x) >> 6);
  int nw = (int)((gridDim.x * blockDim.x) >> 6);
  for (int ii = wid; ii < n; ii += nw) {
    int i = __builtin_amdgcn_readfirstlane(ii);
    float4 acc = make_float4(0.f, 0.f, 0.f, 0.f);
    if (grp == 0 && act) {
      ushort4 u = z4[(size_t)i * 10 + q];          // self term z'[i]
      acc.x = bf2f(u.x); acc.y = bf2f(u.y); acc.z = bf2f(u.z); acc.w = bf2f(u.w);
    }
    int e = rowptr[i] + grp, end = rowptr[i + 1];
    if (act) {
      for (; e + 4 < end; e += 8) {
        int s0 = csr[e], s1 = csr[e + 4];
        ushort4 u0 = z4[(size_t)s0 * 10 + q];
        ushort4 u1 = z4[(size_t)s1 * 10 + q];
        acc.x += bf2f(u0.x) + bf2f(u1.x);
        acc.y += bf2f(u0.y) + bf2f(u1.y);
        acc.z += bf2f(u0.z) + bf2f(u1.z);
        acc.w += bf2f(u0.w) + bf2f(u1.w);
      }
      for (; e < end; e += 4) {
        int s = csr[e];
        ushort4 u = z4[(size_t)s * 10 + q];
        acc.x += bf2f(u.x); acc.y += bf2f(u.y);
        acc.z += bf2f(u.z); acc.w += bf2f(u.w);
      }
    }
    // combine groups (inactive lanes hold zeros everywhere)
    acc.x += __shfl_xor(acc.x, 16); acc.y += __shfl_xor(acc.y, 16);
    acc.z += __shfl_xor(acc.z, 16); acc.w += __shfl_xor(acc.w, 16);
    acc.x += __shfl_xor(acc.x, 32); acc.y += __shfl_xor(acc.y, 32);
    acc.z += __shfl_xor(acc.z, 32); acc.w += __shfl_xor(acc.w, 32);
    float di = dinv[i];
    float4 o;
    o.x = fmaf(di, acc.x, b2v.x);
    o.y = fmaf(di, acc.y, b2v.y);
    o.z = fmaf(di, acc.z, b2v.z);
    o.w = fmaf(di, acc.w, b2v.w);
    // max over 40 ch: per-lane max4, butterfly within 16-lane group
    float m = act ? fmaxf(fmaxf(o.x, o.y), fmaxf(o.z, o.w)) : -INFINITY;
    for (int off = 8; off; off >>= 1) m = fmaxf(m, __shfl_xor(m, off));
    float ex = act ? (expf(o.x - m) + expf(o.y - m) +
                      expf(o.z - m) + expf(o.w - m)) : 0.f;
    float s = ex;
    for (int off = 8; off; off >>= 1) s += __shfl_xor(s, off);
    if (lane < 16 && act) {       // group 0 stores, float4 per lane
      float l = m + logf(s);
      float4 o2 = make_float4(o.x - l, o.y - l, o.z - l, o.w - l);
      *(float4*)&out[(size_t)i * OUT_C + 4 * q] = o2;
    }
  }
}

extern "C" void kernel_launch(void* const* d_in, const int* in_sizes, int n_in,
                              void* d_out, int out_size, void* d_ws, size_t ws_size,
                              hipStream_t stream) {
  const float* x  = (const float*)d_in[0];
  const int* eidx = (const int*)d_in[1];   // harness delivers integers as int32
  const float* W1 = (const float*)d_in[2];
  const float* b1 = (const float*)d_in[3];
  const float* W2 = (const float*)d_in[4];
  const float* b2 = (const float*)d_in[5];
  float* out = (float*)d_out;

  int n = in_sizes[0] / IN_C;
  int E = in_sizes[1] / 2;

  size_t npad = ((size_t)n + 255) & ~(size_t)255;
  size_t Epad = ((size_t)E + 255) & ~(size_t)255;
  // layout (4-byte units)
  size_t o_dinv   = 0;
  size_t o_deg    = o_dinv + npad;
  size_t o_S      = o_deg + npad;
  size_t o_BS     = o_S + npad;
  size_t o_rowptr = o_BS + 256;
  size_t o_cursor = o_rowptr + npad + 256;
  size_t o_csr    = o_cursor + npad;
  size_t o_bufA   = o_csr + Epad;                 // y' bf16: n*64*2B = n*32 words
  size_t o_bufB   = o_bufA + (size_t)n * 32;      // z' bf16: n*40*2B = n*20 words
  size_t needed   = (o_bufB + (size_t)n * 20 + 64) * 4;
  if (ws_size < needed) return;  // fail via absmax, not GPU fault

  float* ws  = (float*)d_ws;
  float* dinv = ws + o_dinv;
  int* deg    = (int*)(ws + o_deg);
  int* S      = (int*)(ws + o_S);
  int* BS     = (int*)(ws + o_BS);
  int* rowptr = (int*)(ws + o_rowptr);
  int* cursor = (int*)(ws + o_cursor);
  int* csr    = (int*)(ws + o_csr);
  u16* bufA   = (u16*)(ws + o_bufA);   // y' bf16 (n x 64)
  u16* bufB   = (u16*)(ws + o_bufB);   // z' bf16 (n x 40)

  int nb = (int)((n + 1023) / 1024);   // 98 for n=100k; scan2 supports <=128

  // ---- CSR build (shared by both layers) ----
  zero4_kernel<<<128, 256, 0, stream>>>((int4*)deg, (long long)(npad / 4));
  deg_kernel<<<2048, 256, 0, stream>>>(eidx + E, E, deg);
  scan1_kernel<<<nb, 256, 0, stream>>>(deg, S, BS, n);
  scan2_kernel<<<1, 128, 0, stream>>>(BS, nb);
  scan3_kernel<<<(n + 255) / 256, 256, 0, stream>>>(S, BS, deg, rowptr, cursor,
                                                    dinv, n);
  fill_kernel<<<2048, 256, 0, stream>>>(eidx, E, cursor, csr);

  // ---- layer 1 GEMM: y' = bf16(dinv * (x @ W1)) ----
  gemm1_kernel<<<(n + 63) / 64, 256, 0, stream>>>(x, W1, dinv, bufA, n);
  // ---- gather(y') + bias/ReLU + z' = bf16(dinv * (h @ W2)) (fused) ----
  gather_gemm2_kernel<<<2048, 256, 0, stream>>>((const ushort4*)bufA, rowptr,
                                                csr, dinv, b1, W2, bufB, n);
  // ---- gather(z') + bias + log-softmax ----
  gather40_kernel<<<2048, 256, 0, stream>>>((const ushort4*)bufB, rowptr, csr,
                                            dinv, b2, out, n);
}

// Round 10
// 223.328 us; speedup vs baseline: 1.0486x; 1.0486x over previous
//
#include <hip/hip_runtime.h>
#include <math.h>

#define IN_C 128
#define HID_C 64
#define OUT_C 40

// ---- grid-stride int4 zero ----
__global__ void zero4_kernel(int4* __restrict__ p, long long n4) {
  long long i = (long long)blockIdx.x * blockDim.x + threadIdx.x;
  long long stride = (long long)gridDim.x * blockDim.x;
  for (; i < n4; i += stride) p[i] = make_int4(0, 0, 0, 0);
}

// ---- degree: count incoming edges (dst side), int atomics ----
__global__ void deg_kernel(const int* __restrict__ dst, int E,
                           int* __restrict__ deg) {
  int i = blockIdx.x * blockDim.x + threadIdx.x;
  int stride = gridDim.x * blockDim.x;
  for (int e = i; e < E; e += stride) atomicAdd(&deg[dst[e]], 1);
}

// ---- scan stage 1: per-1024-chunk inclusive scan + chunk totals ----
__global__ __launch_bounds__(256) void scan1_kernel(
    const int* __restrict__ deg, int* __restrict__ S, int* __restrict__ BS,
    int n) {
  __shared__ int sums[256];
  int t = threadIdx.x;
  int i0 = blockIdx.x * 1024 + t * 4;
  int v0 = (i0 + 0 < n) ? deg[i0 + 0] : 0;
  int v1 = (i0 + 1 < n) ? deg[i0 + 1] : 0;
  int v2 = (i0 + 2 < n) ? deg[i0 + 2] : 0;
  int v3 = (i0 + 3 < n) ? deg[i0 + 3] : 0;
  v1 += v0; v2 += v1; v3 += v2;
  sums[t] = v3;
  __syncthreads();
  for (int off = 1; off < 256; off <<= 1) {
    int x = (t >= off) ? sums[t - off] : 0;
    __syncthreads();
    sums[t] += x;
    __syncthreads();
  }
  int excl = t ? sums[t - 1] : 0;
  if (i0 + 0 < n) S[i0 + 0] = v0 + excl;
  if (i0 + 1 < n) S[i0 + 1] = v1 + excl;
  if (i0 + 2 < n) S[i0 + 2] = v2 + excl;
  if (i0 + 3 < n) S[i0 + 3] = v3 + excl;
  if (t == 255) BS[blockIdx.x] = sums[255];
}

// ---- scan stage 2: exclusive scan of chunk totals (nb <= 128) ----
__global__ __launch_bounds__(128) void scan2_kernel(int* __restrict__ BS,
                                                    int nb) {
  __shared__ int s[128];
  int t = threadIdx.x;
  s[t] = (t < nb) ? BS[t] : 0;
  __syncthreads();
  for (int off = 1; off < 128; off <<= 1) {
    int x = (t >= off) ? s[t - off] : 0;
    __syncthreads();
    s[t] += x;
    __syncthreads();
  }
  if (t < nb) BS[t] = t ? s[t - 1] : 0;
}

// ---- scan stage 3: rowptr + cursor + dinv ----
__global__ void scan3_kernel(const int* __restrict__ S,
                             const int* __restrict__ BS,
                             const int* __restrict__ deg,
                             int* __restrict__ rowptr,
                             int* __restrict__ cursor,
                             float* __restrict__ dinv, int n) {
  int i = blockIdx.x * blockDim.x + threadIdx.x;
  if (i < n) {
    int d = deg[i];
    int r = S[i] + BS[i >> 10];      // inclusive prefix = rowptr[i+1]
    rowptr[i + 1] = r;
    cursor[i] = r - d;               // = rowptr[i]
    dinv[i] = rsqrtf((float)d + 1.0f);
    if (i == 0) rowptr[0] = 0;
  }
}

// ---- CSR fill: bucket src indices by dst ----
__global__ void fill_kernel(const int* __restrict__ eidx, int E,
                            int* __restrict__ cursor, int* __restrict__ csr) {
  int i = blockIdx.x * blockDim.x + threadIdx.x;
  int stride = gridDim.x * blockDim.x;
  for (int e = i; e < E; e += stride) {
    int s = eidx[e];
    int d = eidx[E + e];
    int pos = atomicAdd(&cursor[d], 1);
    csr[pos] = s;
  }
}

// ---- y' = dinv * (x @ W1): 64x64 tile, K chunked by 64, 4x4 reg tile ----
#define XS_LD 68   // 64 + 4: float4-aligned, banks spread
__global__ __launch_bounds__(256) void gemm1_kernel(
    const float* __restrict__ x, const float* __restrict__ W1,
    const float* __restrict__ dinv, float* __restrict__ y, int n) {
  __shared__ float xs[64 * XS_LD];    // 17.4 KiB
  __shared__ float wsh[64 * HID_C];   // 16 KiB, [k][j]
  int t = threadIdx.x;
  int rowBase = blockIdx.x * 64;
  const float4* xf4 = (const float4*)x;
  const float4* wf4 = (const float4*)W1;
  int tx = t & 15, ty = t >> 4;
  int i0 = ty * 4, j0 = tx * 4;
  float acc[4][4];
#pragma unroll
  for (int r = 0; r < 4; ++r)
#pragma unroll
    for (int j = 0; j < 4; ++j) acc[r][j] = 0.f;

  for (int kc = 0; kc < 2; ++kc) {           // K chunks of 64
#pragma unroll
    for (int k = 0; k < 4; ++k) {
      int t4 = t + k * 256;                  // 0..1023
      int row = t4 >> 4, c4 = t4 & 15;
      int gr = rowBase + row;
      if (gr >= n) gr = n - 1;
      *(float4*)&xs[row * XS_LD + c4 * 4] = xf4[(size_t)gr * 32 + kc * 16 + c4];
      *(float4*)&wsh[row * HID_C + c4 * 4] = wf4[(size_t)(kc * 64 + row) * 16 + c4];
    }
    __syncthreads();
#pragma unroll 2
    for (int c4 = 0; c4 < 64; c4 += 4) {
      float4 xv[4], wv[4];
#pragma unroll
      for (int r = 0; r < 4; ++r)
        xv[r] = *(const float4*)&xs[(i0 + r) * XS_LD + c4];
#pragma unroll
      for (int cc = 0; cc < 4; ++cc)
        wv[cc] = *(const float4*)&wsh[(c4 + cc) * HID_C + j0];
#pragma unroll
      for (int r = 0; r < 4; ++r) {
#pragma unroll
        for (int cc = 0; cc < 4; ++cc) {
          float xr = (&xv[r].x)[cc];
          acc[r][0] = fmaf(xr, wv[cc].x, acc[r][0]);
          acc[r][1] = fmaf(xr, wv[cc].y, acc[r][1]);
          acc[r][2] = fmaf(xr, wv[cc].z, acc[r][2]);
          acc[r][3] = fmaf(xr, wv[cc].w, acc[r][3]);
        }
      }
    }
    __syncthreads();
  }
#pragma unroll
  for (int r = 0; r < 4; ++r) {
    int i = rowBase + i0 + r;
    if (i < n) {
      float di = dinv[i];
      float4 v = make_float4(di * acc[r][0], di * acc[r][1],
                             di * acc[r][2], di * acc[r][3]);
      *(float4*)&y[(size_t)i * HID_C + j0] = v;
    }
  }
}

// ---- gather1: h = relu(dinv * gathersum(y') + b1); pure gather, f32 ----
// wave = node; 4 groups of 16 lanes, each takes every 4th edge, float4 ch;
// next-node rowptr/dinv prefetched (software pipeline)
__global__ __launch_bounds__(256) void gather1_kernel(
    const float4* __restrict__ y4, const int* __restrict__ rowptr,
    const int* __restrict__ csr, const float* __restrict__ dinv,
    const float* __restrict__ b1, float* __restrict__ h, int n) {
  int lane = threadIdx.x & 63;
  int grp = lane >> 4;             // 0..3: edge sub-group
  int q = lane & 15;               // channel quad (4q..4q+3)
  float4 b1v = ((const float4*)b1)[q];
  int wid = (int)((blockIdx.x * blockDim.x + threadIdx.x) >> 6);
  int nw = (int)((gridDim.x * blockDim.x) >> 6);
  int ii = wid;
  int e0 = 0, e1 = 0; float di = 0.f;
  if (ii < n) { e0 = rowptr[ii]; e1 = rowptr[ii + 1]; di = dinv[ii]; }
  while (ii < n) {
    int nxt = ii + nw;
    int ne0 = 0, ne1 = 0; float ndi = 0.f;
    if (nxt < n) { ne0 = rowptr[nxt]; ne1 = rowptr[nxt + 1]; ndi = dinv[nxt]; }
    int i = __builtin_amdgcn_readfirstlane(ii);
    float4 acc = make_float4(0.f, 0.f, 0.f, 0.f);
    if (grp == 0) acc = y4[(size_t)i * 16 + q];       // self term y'[i]
    int e = e0 + grp, end = e1;
    for (; e + 4 < end; e += 8) {
      int s0 = csr[e], s1 = csr[e + 4];
      float4 v0 = y4[(size_t)s0 * 16 + q];
      float4 v1 = y4[(size_t)s1 * 16 + q];
      acc.x += v0.x + v1.x;
      acc.y += v0.y + v1.y;
      acc.z += v0.z + v1.z;
      acc.w += v0.w + v1.w;
    }
    for (; e < end; e += 4) {
      int s = csr[e];
      float4 v = y4[(size_t)s * 16 + q];
      acc.x += v.x; acc.y += v.y; acc.z += v.z; acc.w += v.w;
    }
    // combine groups (xor 16, xor 32)
    acc.x += __shfl_xor(acc.x, 16); acc.y += __shfl_xor(acc.y, 16);
    acc.z += __shfl_xor(acc.z, 16); acc.w += __shfl_xor(acc.w, 16);
    acc.x += __shfl_xor(acc.x, 32); acc.y += __shfl_xor(acc.y, 32);
    acc.z += __shfl_xor(acc.z, 32); acc.w += __shfl_xor(acc.w, 32);
    if (grp == 0) {
      float4 hv;
      hv.x = fmaf(di, acc.x, b1v.x); hv.x = hv.x > 0.f ? hv.x : 0.f;
      hv.y = fmaf(di, acc.y, b1v.y); hv.y = hv.y > 0.f ? hv.y : 0.f;
      hv.z = fmaf(di, acc.z, b1v.z); hv.z = hv.z > 0.f ? hv.z : 0.f;
      hv.w = fmaf(di, acc.w, b1v.w); hv.w = hv.w > 0.f ? hv.w : 0.f;
      *(float4*)&h[(size_t)i * HID_C + 4 * q] = hv;
    }
    ii = nxt; e0 = ne0; e1 = ne1; di = ndi;
  }
}

// ---- z' = dinv * (h @ W2): 64-node x 40-col tile, 4x4 reg tile ----
__global__ __launch_bounds__(256) void gemm2_kernel(
    const float* __restrict__ h, const float* __restrict__ W2,
    const float* __restrict__ dinv, float* __restrict__ z, int n) {
  __shared__ float hs[64 * XS_LD];      // 17.4 KiB
  __shared__ float w2s[64 * OUT_C + 32];  // 10.4 KiB (+pad for idle-lane reads)
  int t = threadIdx.x;
  int rowBase = blockIdx.x * 64;
  const float4* hf4 = (const float4*)h;
  const float4* wf4 = (const float4*)W2;
  // stage h tile (64 rows x 16 float4) and W2 (640 float4)
#pragma unroll
  for (int k = 0; k < 4; ++k) {
    int t4 = t + k * 256;
    int row = t4 >> 4, c4 = t4 & 15;
    int gr = rowBase + row;
    if (gr >= n) gr = n - 1;
    *(float4*)&hs[row * XS_LD + c4 * 4] = hf4[(size_t)gr * 16 + c4];
  }
  for (int t4 = t; t4 < 640; t4 += 256)
    *(float4*)&w2s[t4 * 4] = wf4[t4];
  __syncthreads();
  int tx = t & 15, ty = t >> 4;
  int i0 = ty * 4, j0 = tx * 4;
  bool active = tx < 10;               // 40 cols = 10 quads
  float acc[4][4];
#pragma unroll
  for (int r = 0; r < 4; ++r)
#pragma unroll
    for (int j = 0; j < 4; ++j) acc[r][j] = 0.f;
#pragma unroll 2
  for (int c4 = 0; c4 < 64; c4 += 4) {
    float4 hv[4], wv[4];
#pragma unroll
    for (int r = 0; r < 4; ++r)
      hv[r] = *(const float4*)&hs[(i0 + r) * XS_LD + c4];
#pragma unroll
    for (int cc = 0; cc < 4; ++cc)
      wv[cc] = *(const float4*)&w2s[(c4 + cc) * OUT_C + j0];
#pragma unroll
    for (int r = 0; r < 4; ++r) {
#pragma unroll
      for (int cc = 0; cc < 4; ++cc) {
        float hr = (&hv[r].x)[cc];
        acc[r][0] = fmaf(hr, wv[cc].x, acc[r][0]);
        acc[r][1] = fmaf(hr, wv[cc].y, acc[r][1]);
        acc[r][2] = fmaf(hr, wv[cc].z, acc[r][2]);
        acc[r][3] = fmaf(hr, wv[cc].w, acc[r][3]);
      }
    }
  }
  if (active) {
#pragma unroll
    for (int r = 0; r < 4; ++r) {
      int i = rowBase + i0 + r;
      if (i < n) {
        float di = dinv[i];
        float4 v = make_float4(di * acc[r][0], di * acc[r][1],
                               di * acc[r][2], di * acc[r][3]);
        *(float4*)&z[(size_t)i * OUT_C + j0] = v;
      }
    }
  }
}

// ---- gather(z') + bias + log-softmax: 4 groups, q<10 active, prefetch ----
__global__ __launch_bounds__(256) void gather40_kernel(
    const float4* __restrict__ z4, const int* __restrict__ rowptr,
    const int* __restrict__ csr, const float* __restrict__ dinv,
    const float* __restrict__ b2, float* __restrict__ out, int n) {
  int lane = threadIdx.x & 63;
  int grp = lane >> 4;             // 0..3: edge sub-group
  int q = lane & 15;               // channel quad; active q<10 (40 ch)
  bool act = q < 10;
  float4 b2v = ((const float4*)b2)[act ? q : 0];
  int wid = (int)((blockIdx.x * blockDim.x + threadIdx.x) >> 6);
  int nw = (int)((gridDim.x * blockDim.x) >> 6);
  int ii = wid;
  int e0 = 0, e1 = 0; float di = 0.f;
  if (ii < n) { e0 = rowptr[ii]; e1 = rowptr[ii + 1]; di = dinv[ii]; }
  while (ii < n) {
    int nxt = ii + nw;
    int ne0 = 0, ne1 = 0; float ndi = 0.f;
    if (nxt < n) { ne0 = rowptr[nxt]; ne1 = rowptr[nxt + 1]; ndi = dinv[nxt]; }
    int i = __builtin_amdgcn_readfirstlane(ii);
    float4 acc = make_float4(0.f, 0.f, 0.f, 0.f);
    if (grp == 0 && act) acc = z4[(size_t)i * 10 + q];    // self term z'[i]
    int e = e0 + grp, end = e1;
    if (act) {
      for (; e + 4 < end; e += 8) {
        int s0 = csr[e], s1 = csr[e + 4];
        float4 v0 = z4[(size_t)s0 * 10 + q];
        float4 v1 = z4[(size_t)s1 * 10 + q];
        acc.x += v0.x + v1.x;
        acc.y += v0.y + v1.y;
        acc.z += v0.z + v1.z;
        acc.w += v0.w + v1.w;
      }
      for (; e < end; e += 4) {
        int s = csr[e];
        float4 v = z4[(size_t)s * 10 + q];
        acc.x += v.x; acc.y += v.y; acc.z += v.z; acc.w += v.w;
      }
    }
    // combine groups (inactive lanes hold zeros everywhere)
    acc.x += __shfl_xor(acc.x, 16); acc.y += __shfl_xor(acc.y, 16);
    acc.z += __shfl_xor(acc.z, 16); acc.w += __shfl_xor(acc.w, 16);
    acc.x += __shfl_xor(acc.x, 32); acc.y += __shfl_xor(acc.y, 32);
    acc.z += __shfl_xor(acc.z, 32); acc.w += __shfl_xor(acc.w, 32);
    float4 o;
    o.x = fmaf(di, acc.x, b2v.x);
    o.y = fmaf(di, acc.y, b2v.y);
    o.z = fmaf(di, acc.z, b2v.z);
    o.w = fmaf(di, acc.w, b2v.w);
    // max over 40 ch: per-lane max4, butterfly within 16-lane group
    float m = act ? fmaxf(fmaxf(o.x, o.y), fmaxf(o.z, o.w)) : -INFINITY;
    for (int off = 8; off; off >>= 1) m = fmaxf(m, __shfl_xor(m, off));
    float ex = act ? (expf(o.x - m) + expf(o.y - m) +
                      expf(o.z - m) + expf(o.w - m)) : 0.f;
    float s = ex;
    for (int off = 8; off; off >>= 1) s += __shfl_xor(s, off);
    if (lane < 16 && act) {       // group 0 stores, float4 per lane
      float l = m + logf(s);
      float4 o2 = make_float4(o.x - l, o.y - l, o.z - l, o.w - l);
      *(float4*)&out[(size_t)i * OUT_C + 4 * q] = o2;
    }
    ii = nxt; e0 = ne0; e1 = ne1; di = ndi;
  }
}

extern "C" void kernel_launch(void* const* d_in, const int* in_sizes, int n_in,
                              void* d_out, int out_size, void* d_ws, size_t ws_size,
                              hipStream_t stream) {
  const float* x  = (const float*)d_in[0];
  const int* eidx = (const int*)d_in[1];   // harness delivers integers as int32
  const float* W1 = (const float*)d_in[2];
  const float* b1 = (const float*)d_in[3];
  const float* W2 = (const float*)d_in[4];
  const float* b2 = (const float*)d_in[5];
  float* out = (float*)d_out;

  int n = in_sizes[0] / IN_C;
  int E = in_sizes[1] / 2;

  size_t npad = ((size_t)n + 255) & ~(size_t)255;
  size_t Epad = ((size_t)E + 255) & ~(size_t)255;
  // layout (4-byte units)
  size_t o_dinv   = 0;
  size_t o_deg    = o_dinv + npad;
  size_t o_S      = o_deg + npad;
  size_t o_BS     = o_S + npad;
  size_t o_rowptr = o_BS + 256;
  size_t o_cursor = o_rowptr + npad + 256;
  size_t o_csr    = o_cursor + npad;
  size_t o_bufA   = o_csr + Epad;                 // y' then z' (n x 64 f32)
  size_t o_bufC   = o_bufA + (size_t)n * HID_C;   // h (n x 64 f32)
  size_t needed   = (o_bufC + (size_t)n * HID_C) * 4;
  if (ws_size < needed) return;  // fail via absmax, not GPU fault

  float* ws  = (float*)d_ws;
  float* dinv = ws + o_dinv;
  int* deg    = (int*)(ws + o_deg);
  int* S      = (int*)(ws + o_S);
  int* BS     = (int*)(ws + o_BS);
  int* rowptr = (int*)(ws + o_rowptr);
  int* cursor = (int*)(ws + o_cursor);
  int* csr    = (int*)(ws + o_csr);
  float* bufA = ws + o_bufA;   // y' (n x 64) -> z' (n x 40)
  float* bufC = ws + o_bufC;   // h (n x 64)

  int nb = (int)((n + 1023) / 1024);   // 98 for n=100k; scan2 supports <=128

  // ---- CSR build (shared by both layers) ----
  zero4_kernel<<<128, 256, 0, stream>>>((int4*)deg, (long long)(npad / 4));
  deg_kernel<<<2048, 256, 0, stream>>>(eidx + E, E, deg);
  scan1_kernel<<<nb, 256, 0, stream>>>(deg, S, BS, n);
  scan2_kernel<<<1, 128, 0, stream>>>(BS, nb);
  scan3_kernel<<<(n + 255) / 256, 256, 0, stream>>>(S, BS, deg, rowptr, cursor,
                                                    dinv, n);
  fill_kernel<<<2048, 256, 0, stream>>>(eidx, E, cursor, csr);

  // ---- layer 1: y' = dinv*(x@W1) ; h = relu(dinv*gather(y') + b1) ----
  gemm1_kernel<<<(n + 63) / 64, 256, 0, stream>>>(x, W1, dinv, bufA, n);
  gather1_kernel<<<2048, 256, 0, stream>>>((const float4*)bufA, rowptr, csr,
                                           dinv, b1, bufC, n);
  // ---- layer 2: z' = dinv*(h@W2) ; out = logsoftmax(dinv*gather(z')+b2) ----
  gemm2_kernel<<<(n + 63) / 64, 256, 0, stream>>>(bufC, W2, dinv, bufA, n);
  gather40_kernel<<<2048, 256, 0, stream>>>((const float4*)bufA, rowptr, csr,
                                            dinv, b2, out, n);
}

// Round 11
// 212.834 us; speedup vs baseline: 1.1003x; 1.0493x over previous
//
#include <hip/hip_runtime.h>
#include <math.h>

#define IN_C 128
#define HID_C 64
#define OUT_C 40

// ---- grid-stride int4 zero ----
__global__ void zero4_kernel(int4* __restrict__ p, long long n4) {
  long long i = (long long)blockIdx.x * blockDim.x + threadIdx.x;
  long long stride = (long long)gridDim.x * blockDim.x;
  for (; i < n4; i += stride) p[i] = make_int4(0, 0, 0, 0);
}

// ---- degree: count incoming edges (dst side), int atomics ----
__global__ void deg_kernel(const int* __restrict__ dst, int E,
                           int* __restrict__ deg) {
  int i = blockIdx.x * blockDim.x + threadIdx.x;
  int stride = gridDim.x * blockDim.x;
  for (int e = i; e < E; e += stride) atomicAdd(&deg[dst[e]], 1);
}

// ---- scan stage 1: per-1024-chunk inclusive scan + chunk totals ----
__global__ __launch_bounds__(256) void scan1_kernel(
    const int* __restrict__ deg, int* __restrict__ S, int* __restrict__ BS,
    int n) {
  __shared__ int sums[256];
  int t = threadIdx.x;
  int i0 = blockIdx.x * 1024 + t * 4;
  int v0 = (i0 + 0 < n) ? deg[i0 + 0] : 0;
  int v1 = (i0 + 1 < n) ? deg[i0 + 1] : 0;
  int v2 = (i0 + 2 < n) ? deg[i0 + 2] : 0;
  int v3 = (i0 + 3 < n) ? deg[i0 + 3] : 0;
  v1 += v0; v2 += v1; v3 += v2;
  sums[t] = v3;
  __syncthreads();
  for (int off = 1; off < 256; off <<= 1) {
    int x = (t >= off) ? sums[t - off] : 0;
    __syncthreads();
    sums[t] += x;
    __syncthreads();
  }
  int excl = t ? sums[t - 1] : 0;
  if (i0 + 0 < n) S[i0 + 0] = v0 + excl;
  if (i0 + 1 < n) S[i0 + 1] = v1 + excl;
  if (i0 + 2 < n) S[i0 + 2] = v2 + excl;
  if (i0 + 3 < n) S[i0 + 3] = v3 + excl;
  if (t == 255) BS[blockIdx.x] = sums[255];
}

// ---- scan stage 2: exclusive scan of chunk totals (nb <= 128) ----
__global__ __launch_bounds__(128) void scan2_kernel(int* __restrict__ BS,
                                                    int nb) {
  __shared__ int s[128];
  int t = threadIdx.x;
  s[t] = (t < nb) ? BS[t] : 0;
  __syncthreads();
  for (int off = 1; off < 128; off <<= 1) {
    int x = (t >= off) ? s[t - off] : 0;
    __syncthreads();
    s[t] += x;
    __syncthreads();
  }
  if (t < nb) BS[t] = t ? s[t - 1] : 0;
}

// ---- scan stage 3: rowptr + cursor + dinv ----
__global__ void scan3_kernel(const int* __restrict__ S,
                             const int* __restrict__ BS,
                             const int* __restrict__ deg,
                             int* __restrict__ rowptr,
                             int* __restrict__ cursor,
                             float* __restrict__ dinv, int n) {
  int i = blockIdx.x * blockDim.x + threadIdx.x;
  if (i < n) {
    int d = deg[i];
    int r = S[i] + BS[i >> 10];      // inclusive prefix = rowptr[i+1]
    rowptr[i + 1] = r;
    cursor[i] = r - d;               // = rowptr[i]
    dinv[i] = rsqrtf((float)d + 1.0f);
    if (i == 0) rowptr[0] = 0;
  }
}

// ---- fused: blocks [0,fillBlocks) do CSR fill (4-deep MLP unroll);
//      blocks [fillBlocks,...) do y = x @ W1 (raw, no dinv) ----
#define XS_LD 68   // 64 + 4: float4-aligned, banks spread
#define FILL_BLOCKS 1024
__global__ __launch_bounds__(256) void fused_fill_gemm1_kernel(
    const int* __restrict__ eidx, int E, int* __restrict__ cursor,
    int* __restrict__ csr, const float* __restrict__ x,
    const float* __restrict__ W1, float* __restrict__ y, int n) {
  __shared__ float xs[64 * XS_LD];    // 17.4 KiB
  __shared__ float wsh[64 * HID_C];   // 16 KiB, [k][j]
  int t = threadIdx.x;
  if ((int)blockIdx.x < FILL_BLOCKS) {
    // ---- CSR fill: 4 edges per thread, atomics issued back-to-back ----
    int base = blockIdx.x * 256 + t;
    int stride = FILL_BLOCKS * 256;
    for (int e = base; e < E; e += 4 * stride) {
      int s0, s1, s2, s3, d0, d1, d2, d3;
      int e1 = e + stride, e2 = e + 2 * stride, e3 = e + 3 * stride;
      bool g1 = e1 < E, g2 = e2 < E, g3 = e3 < E;
      s0 = eidx[e]; d0 = eidx[E + e];
      if (g1) { s1 = eidx[e1]; d1 = eidx[E + e1]; }
      if (g2) { s2 = eidx[e2]; d2 = eidx[E + e2]; }
      if (g3) { s3 = eidx[e3]; d3 = eidx[E + e3]; }
      int p0, p1, p2, p3;
      p0 = atomicAdd(&cursor[d0], 1);
      if (g1) p1 = atomicAdd(&cursor[d1], 1);
      if (g2) p2 = atomicAdd(&cursor[d2], 1);
      if (g3) p3 = atomicAdd(&cursor[d3], 1);
      csr[p0] = s0;
      if (g1) csr[p1] = s1;
      if (g2) csr[p2] = s2;
      if (g3) csr[p3] = s3;
    }
    return;
  }
  // ---- GEMM1: 64x64 tile, K chunked by 64, 4x4 reg tile ----
  int rowBase = ((int)blockIdx.x - FILL_BLOCKS) * 64;
  const float4* xf4 = (const float4*)x;
  const float4* wf4 = (const float4*)W1;
  int tx = t & 15, ty = t >> 4;
  int i0 = ty * 4, j0 = tx * 4;
  float acc[4][4];
#pragma unroll
  for (int r = 0; r < 4; ++r)
#pragma unroll
    for (int j = 0; j < 4; ++j) acc[r][j] = 0.f;

  for (int kc = 0; kc < 2; ++kc) {           // K chunks of 64
#pragma unroll
    for (int k = 0; k < 4; ++k) {
      int t4 = t + k * 256;                  // 0..1023
      int row = t4 >> 4, c4 = t4 & 15;
      int gr = rowBase + row;
      if (gr >= n) gr = n - 1;
      *(float4*)&xs[row * XS_LD + c4 * 4] = xf4[(size_t)gr * 32 + kc * 16 + c4];
      *(float4*)&wsh[row * HID_C + c4 * 4] = wf4[(size_t)(kc * 64 + row) * 16 + c4];
    }
    __syncthreads();
#pragma unroll 2
    for (int c4 = 0; c4 < 64; c4 += 4) {
      float4 xv[4], wv[4];
#pragma unroll
      for (int r = 0; r < 4; ++r)
        xv[r] = *(const float4*)&xs[(i0 + r) * XS_LD + c4];
#pragma unroll
      for (int cc = 0; cc < 4; ++cc)
        wv[cc] = *(const float4*)&wsh[(c4 + cc) * HID_C + j0];
#pragma unroll
      for (int r = 0; r < 4; ++r) {
#pragma unroll
        for (int cc = 0; cc < 4; ++cc) {
          float xr = (&xv[r].x)[cc];
          acc[r][0] = fmaf(xr, wv[cc].x, acc[r][0]);
          acc[r][1] = fmaf(xr, wv[cc].y, acc[r][1]);
          acc[r][2] = fmaf(xr, wv[cc].z, acc[r][2]);
          acc[r][3] = fmaf(xr, wv[cc].w, acc[r][3]);
        }
      }
    }
    __syncthreads();
  }
#pragma unroll
  for (int r = 0; r < 4; ++r) {
    int i = rowBase + i0 + r;
    if (i < n) {
      float4 v = make_float4(acc[r][0], acc[r][1], acc[r][2], acc[r][3]);
      *(float4*)&y[(size_t)i * HID_C + j0] = v;
    }
  }
}

// ---- gather1: h = relu(dinv[i] * Σ dinv[s]*y[s] + b1)  (y raw f32) ----
// wave = node; 4 groups of 16 lanes, each takes every 4th edge, float4 ch;
// next-node rowptr/dinv prefetched (software pipeline)
__global__ __launch_bounds__(256) void gather1_kernel(
    const float4* __restrict__ y4, const int* __restrict__ rowptr,
    const int* __restrict__ csr, const float* __restrict__ dinv,
    const float* __restrict__ b1, float* __restrict__ h, int n) {
  int lane = threadIdx.x & 63;
  int grp = lane >> 4;             // 0..3: edge sub-group
  int q = lane & 15;               // channel quad (4q..4q+3)
  float4 b1v = ((const float4*)b1)[q];
  int wid = (int)((blockIdx.x * blockDim.x + threadIdx.x) >> 6);
  int nw = (int)((gridDim.x * blockDim.x) >> 6);
  int ii = wid;
  int e0 = 0, e1 = 0; float di = 0.f;
  if (ii < n) { e0 = rowptr[ii]; e1 = rowptr[ii + 1]; di = dinv[ii]; }
  while (ii < n) {
    int nxt = ii + nw;
    int ne0 = 0, ne1 = 0; float ndi = 0.f;
    if (nxt < n) { ne0 = rowptr[nxt]; ne1 = rowptr[nxt + 1]; ndi = dinv[nxt]; }
    int i = __builtin_amdgcn_readfirstlane(ii);
    float4 acc = make_float4(0.f, 0.f, 0.f, 0.f);
    if (grp == 0) {                // self term: di * y[i]
      float4 v = y4[(size_t)i * 16 + q];
      acc.x = di * v.x; acc.y = di * v.y; acc.z = di * v.z; acc.w = di * v.w;
    }
    int e = e0 + grp, end = e1;
    for (; e + 4 < end; e += 8) {
      int s0 = csr[e], s1 = csr[e + 4];
      float ds0 = dinv[s0], ds1 = dinv[s1];
      float4 v0 = y4[(size_t)s0 * 16 + q];
      float4 v1 = y4[(size_t)s1 * 16 + q];
      acc.x = fmaf(ds0, v0.x, fmaf(ds1, v1.x, acc.x));
      acc.y = fmaf(ds0, v0.y, fmaf(ds1, v1.y, acc.y));
      acc.z = fmaf(ds0, v0.z, fmaf(ds1, v1.z, acc.z));
      acc.w = fmaf(ds0, v0.w, fmaf(ds1, v1.w, acc.w));
    }
    for (; e < end; e += 4) {
      int s = csr[e];
      float ds = dinv[s];
      float4 v = y4[(size_t)s * 16 + q];
      acc.x = fmaf(ds, v.x, acc.x);
      acc.y = fmaf(ds, v.y, acc.y);
      acc.z = fmaf(ds, v.z, acc.z);
      acc.w = fmaf(ds, v.w, acc.w);
    }
    // combine groups (xor 16, xor 32)
    acc.x += __shfl_xor(acc.x, 16); acc.y += __shfl_xor(acc.y, 16);
    acc.z += __shfl_xor(acc.z, 16); acc.w += __shfl_xor(acc.w, 16);
    acc.x += __shfl_xor(acc.x, 32); acc.y += __shfl_xor(acc.y, 32);
    acc.z += __shfl_xor(acc.z, 32); acc.w += __shfl_xor(acc.w, 32);
    if (grp == 0) {
      float4 hv;
      hv.x = fmaf(di, acc.x, b1v.x); hv.x = hv.x > 0.f ? hv.x : 0.f;
      hv.y = fmaf(di, acc.y, b1v.y); hv.y = hv.y > 0.f ? hv.y : 0.f;
      hv.z = fmaf(di, acc.z, b1v.z); hv.z = hv.z > 0.f ? hv.z : 0.f;
      hv.w = fmaf(di, acc.w, b1v.w); hv.w = hv.w > 0.f ? hv.w : 0.f;
      *(float4*)&h[(size_t)i * HID_C + 4 * q] = hv;
    }
    ii = nxt; e0 = ne0; e1 = ne1; di = ndi;
  }
}

// ---- z' = dinv * (h @ W2): 64-node x 40-col tile, 4x4 reg tile ----
__global__ __launch_bounds__(256) void gemm2_kernel(
    const float* __restrict__ h, const float* __restrict__ W2,
    const float* __restrict__ dinv, float* __restrict__ z, int n) {
  __shared__ float hs[64 * XS_LD];      // 17.4 KiB
  __shared__ float w2s[64 * OUT_C + 32];  // 10.4 KiB (+pad for idle-lane reads)
  int t = threadIdx.x;
  int rowBase = blockIdx.x * 64;
  const float4* hf4 = (const float4*)h;
  const float4* wf4 = (const float4*)W2;
#pragma unroll
  for (int k = 0; k < 4; ++k) {
    int t4 = t + k * 256;
    int row = t4 >> 4, c4 = t4 & 15;
    int gr = rowBase + row;
    if (gr >= n) gr = n - 1;
    *(float4*)&hs[row * XS_LD + c4 * 4] = hf4[(size_t)gr * 16 + c4];
  }
  for (int t4 = t; t4 < 640; t4 += 256)
    *(float4*)&w2s[t4 * 4] = wf4[t4];
  __syncthreads();
  int tx = t & 15, ty = t >> 4;
  int i0 = ty * 4, j0 = tx * 4;
  bool active = tx < 10;               // 40 cols = 10 quads
  float acc[4][4];
#pragma unroll
  for (int r = 0; r < 4; ++r)
#pragma unroll
    for (int j = 0; j < 4; ++j) acc[r][j] = 0.f;
#pragma unroll 2
  for (int c4 = 0; c4 < 64; c4 += 4) {
    float4 hv[4], wv[4];
#pragma unroll
    for (int r = 0; r < 4; ++r)
      hv[r] = *(const float4*)&hs[(i0 + r) * XS_LD + c4];
#pragma unroll
    for (int cc = 0; cc < 4; ++cc)
      wv[cc] = *(const float4*)&w2s[(c4 + cc) * OUT_C + j0];
#pragma unroll
    for (int r = 0; r < 4; ++r) {
#pragma unroll
      for (int cc = 0; cc < 4; ++cc) {
        float hr = (&hv[r].x)[cc];
        acc[r][0] = fmaf(hr, wv[cc].x, acc[r][0]);
        acc[r][1] = fmaf(hr, wv[cc].y, acc[r][1]);
        acc[r][2] = fmaf(hr, wv[cc].z, acc[r][2]);
        acc[r][3] = fmaf(hr, wv[cc].w, acc[r][3]);
      }
    }
  }
  if (active) {
#pragma unroll
    for (int r = 0; r < 4; ++r) {
      int i = rowBase + i0 + r;
      if (i < n) {
        float di = dinv[i];
        float4 v = make_float4(di * acc[r][0], di * acc[r][1],
                               di * acc[r][2], di * acc[r][3]);
        *(float4*)&z[(size_t)i * OUT_C + j0] = v;
      }
    }
  }
}

// ---- gather(z') + bias + log-softmax: 4 groups, q<10 active, prefetch ----
__global__ __launch_bounds__(256) void gather40_kernel(
    const float4* __restrict__ z4, const int* __restrict__ rowptr,
    const int* __restrict__ csr, const float* __restrict__ dinv,
    const float* __restrict__ b2, float* __restrict__ out, int n) {
  int lane = threadIdx.x & 63;
  int grp = lane >> 4;             // 0..3: edge sub-group
  int q = lane & 15;               // channel quad; active q<10 (40 ch)
  bool act = q < 10;
  float4 b2v = ((const float4*)b2)[act ? q : 0];
  int wid = (int)((blockIdx.x * blockDim.x + threadIdx.x) >> 6);
  int nw = (int)((gridDim.x * blockDim.x) >> 6);
  int ii = wid;
  int e0 = 0, e1 = 0; float di = 0.f;
  if (ii < n) { e0 = rowptr[ii]; e1 = rowptr[ii + 1]; di = dinv[ii]; }
  while (ii < n) {
    int nxt = ii + nw;
    int ne0 = 0, ne1 = 0; float ndi = 0.f;
    if (nxt < n) { ne0 = rowptr[nxt]; ne1 = rowptr[nxt + 1]; ndi = dinv[nxt]; }
    int i = __builtin_amdgcn_readfirstlane(ii);
    float4 acc = make_float4(0.f, 0.f, 0.f, 0.f);
    if (grp == 0 && act) acc = z4[(size_t)i * 10 + q];    // self term z'[i]
    int e = e0 + grp, end = e1;
    if (act) {
      for (; e + 4 < end; e += 8) {
        int s0 = csr[e], s1 = csr[e + 4];
        float4 v0 = z4[(size_t)s0 * 10 + q];
        float4 v1 = z4[(size_t)s1 * 10 + q];
        acc.x += v0.x + v1.x;
        acc.y += v0.y + v1.y;
        acc.z += v0.z + v1.z;
        acc.w += v0.w + v1.w;
      }
      for (; e < end; e += 4) {
        int s = csr[e];
        float4 v = z4[(size_t)s * 10 + q];
        acc.x += v.x; acc.y += v.y; acc.z += v.z; acc.w += v.w;
      }
    }
    // combine groups (inactive lanes hold zeros everywhere)
    acc.x += __shfl_xor(acc.x, 16); acc.y += __shfl_xor(acc.y, 16);
    acc.z += __shfl_xor(acc.z, 16); acc.w += __shfl_xor(acc.w, 16);
    acc.x += __shfl_xor(acc.x, 32); acc.y += __shfl_xor(acc.y, 32);
    acc.z += __shfl_xor(acc.z, 32); acc.w += __shfl_xor(acc.w, 32);
    float4 o;
    o.x = fmaf(di, acc.x, b2v.x);
    o.y = fmaf(di, acc.y, b2v.y);
    o.z = fmaf(di, acc.z, b2v.z);
    o.w = fmaf(di, acc.w, b2v.w);
    // max over 40 ch: per-lane max4, butterfly within 16-lane group
    float m = act ? fmaxf(fmaxf(o.x, o.y), fmaxf(o.z, o.w)) : -INFINITY;
    for (int off = 8; off; off >>= 1) m = fmaxf(m, __shfl_xor(m, off));
    float ex = act ? (expf(o.x - m) + expf(o.y - m) +
                      expf(o.z - m) + expf(o.w - m)) : 0.f;
    float s = ex;
    for (int off = 8; off; off >>= 1) s += __shfl_xor(s, off);
    if (lane < 16 && act) {       // group 0 stores, float4 per lane
      float l = m + logf(s);
      float4 o2 = make_float4(o.x - l, o.y - l, o.z - l, o.w - l);
      *(float4*)&out[(size_t)i * OUT_C + 4 * q] = o2;
    }
    ii = nxt; e0 = ne0; e1 = ne1; di = ndi;
  }
}

extern "C" void kernel_launch(void* const* d_in, const int* in_sizes, int n_in,
                              void* d_out, int out_size, void* d_ws, size_t ws_size,
                              hipStream_t stream) {
  const float* x  = (const float*)d_in[0];
  const int* eidx = (const int*)d_in[1];   // harness delivers integers as int32
  const float* W1 = (const float*)d_in[2];
  const float* b1 = (const float*)d_in[3];
  const float* W2 = (const float*)d_in[4];
  const float* b2 = (const float*)d_in[5];
  float* out = (float*)d_out;

  int n = in_sizes[0] / IN_C;
  int E = in_sizes[1] / 2;

  size_t npad = ((size_t)n + 255) & ~(size_t)255;
  size_t Epad = ((size_t)E + 255) & ~(size_t)255;
  // layout (4-byte units)
  size_t o_dinv   = 0;
  size_t o_deg    = o_dinv + npad;
  size_t o_S      = o_deg + npad;
  size_t o_BS     = o_S + npad;
  size_t o_rowptr = o_BS + 256;
  size_t o_cursor = o_rowptr + npad + 256;
  size_t o_csr    = o_cursor + npad;
  size_t o_bufA   = o_csr + Epad;                 // y raw, then z' (n x 64 f32)
  size_t o_bufC   = o_bufA + (size_t)n * HID_C;   // h (n x 64 f32)
  size_t needed   = (o_bufC + (size_t)n * HID_C) * 4;
  if (ws_size < needed) return;  // fail via absmax, not GPU fault

  float* ws  = (float*)d_ws;
  float* dinv = ws + o_dinv;
  int* deg    = (int*)(ws + o_deg);
  int* S      = (int*)(ws + o_S);
  int* BS     = (int*)(ws + o_BS);
  int* rowptr = (int*)(ws + o_rowptr);
  int* cursor = (int*)(ws + o_cursor);
  int* csr    = (int*)(ws + o_csr);
  float* bufA = ws + o_bufA;   // y (n x 64) -> z' (n x 40)
  float* bufC = ws + o_bufC;   // h (n x 64)

  int nb = (int)((n + 1023) / 1024);   // 98 for n=100k; scan2 supports <=128

  // ---- CSR build prefix ----
  zero4_kernel<<<128, 256, 0, stream>>>((int4*)deg, (long long)(npad / 4));
  deg_kernel<<<2048, 256, 0, stream>>>(eidx + E, E, deg);
  scan1_kernel<<<nb, 256, 0, stream>>>(deg, S, BS, n);
  scan2_kernel<<<1, 128, 0, stream>>>(BS, nb);
  scan3_kernel<<<(n + 255) / 256, 256, 0, stream>>>(S, BS, deg, rowptr, cursor,
                                                    dinv, n);

  // ---- fused: CSR fill (MLP-unrolled) || y = x @ W1 (raw) ----
  int gemmBlocks = (n + 63) / 64;
  fused_fill_gemm1_kernel<<<FILL_BLOCKS + gemmBlocks, 256, 0, stream>>>(
      eidx, E, cursor, csr, x, W1, bufA, n);

  // ---- layer 1 gather: h = relu(dinv_i * sum(dinv_s * y_s) + b1) ----
  gather1_kernel<<<2048, 256, 0, stream>>>((const float4*)bufA, rowptr, csr,
                                           dinv, b1, bufC, n);
  // ---- layer 2: z' = dinv*(h@W2) ; out = logsoftmax(dinv*gather(z')+b2) ----
  gemm2_kernel<<<(n + 63) / 64, 256, 0, stream>>>(bufC, W2, dinv, bufA, n);
  gather40_kernel<<<2048, 256, 0, stream>>>((const float4*)bufA, rowptr, csr,
                                            dinv, b2, out, n);
}

// Round 12
// 181.986 us; speedup vs baseline: 1.2869x; 1.1695x over previous
//
#include <hip/hip_runtime.h>
#include <math.h>

#define IN_C 128
#define HID_C 64
#define OUT_C 40

// ---- grid-stride int4 zero ----
__global__ void zero4_kernel(int4* __restrict__ p, long long n4) {
  long long i = (long long)blockIdx.x * blockDim.x + threadIdx.x;
  long long stride = (long long)gridDim.x * blockDim.x;
  for (; i < n4; i += stride) p[i] = make_int4(0, 0, 0, 0);
}

// ---- degree + per-edge slot: pos[e] = atomicAdd(deg[dst],1); pos coalesced ----
__global__ void degpos_kernel(const int* __restrict__ dst, int E,
                              int* __restrict__ deg, int* __restrict__ pos) {
  int base = blockIdx.x * blockDim.x + threadIdx.x;
  int stride = gridDim.x * blockDim.x;
  for (int e = base; e < E; e += 4 * stride) {
    int e1 = e + stride, e2 = e + 2 * stride, e3 = e + 3 * stride;
    bool g1 = e1 < E, g2 = e2 < E, g3 = e3 < E;
    int d0 = dst[e];
    int d1 = g1 ? dst[e1] : 0;
    int d2 = g2 ? dst[e2] : 0;
    int d3 = g3 ? dst[e3] : 0;
    int p0 = atomicAdd(&deg[d0], 1);
    int p1 = g1 ? atomicAdd(&deg[d1], 1) : 0;
    int p2 = g2 ? atomicAdd(&deg[d2], 1) : 0;
    int p3 = g3 ? atomicAdd(&deg[d3], 1) : 0;
    pos[e] = p0;                    // coalesced stores
    if (g1) pos[e1] = p1;
    if (g2) pos[e2] = p2;
    if (g3) pos[e3] = p3;
  }
}

// ---- scan stage 1: per-1024-chunk inclusive scan + chunk totals ----
__global__ __launch_bounds__(256) void scan1_kernel(
    const int* __restrict__ deg, int* __restrict__ S, int* __restrict__ BS,
    int n) {
  __shared__ int sums[256];
  int t = threadIdx.x;
  int i0 = blockIdx.x * 1024 + t * 4;
  int v0 = (i0 + 0 < n) ? deg[i0 + 0] : 0;
  int v1 = (i0 + 1 < n) ? deg[i0 + 1] : 0;
  int v2 = (i0 + 2 < n) ? deg[i0 + 2] : 0;
  int v3 = (i0 + 3 < n) ? deg[i0 + 3] : 0;
  v1 += v0; v2 += v1; v3 += v2;
  sums[t] = v3;
  __syncthreads();
  for (int off = 1; off < 256; off <<= 1) {
    int x = (t >= off) ? sums[t - off] : 0;
    __syncthreads();
    sums[t] += x;
    __syncthreads();
  }
  int excl = t ? sums[t - 1] : 0;
  if (i0 + 0 < n) S[i0 + 0] = v0 + excl;
  if (i0 + 1 < n) S[i0 + 1] = v1 + excl;
  if (i0 + 2 < n) S[i0 + 2] = v2 + excl;
  if (i0 + 3 < n) S[i0 + 3] = v3 + excl;
  if (t == 255) BS[blockIdx.x] = sums[255];
}

// ---- scan stage 2: exclusive scan of chunk totals (nb <= 128) ----
__global__ __launch_bounds__(128) void scan2_kernel(int* __restrict__ BS,
                                                    int nb) {
  __shared__ int s[128];
  int t = threadIdx.x;
  s[t] = (t < nb) ? BS[t] : 0;
  __syncthreads();
  for (int off = 1; off < 128; off <<= 1) {
    int x = (t >= off) ? s[t - off] : 0;
    __syncthreads();
    s[t] += x;
    __syncthreads();
  }
  if (t < nb) BS[t] = t ? s[t - 1] : 0;
}

// ---- scan stage 3: rowptr + dinv ----
__global__ void scan3_kernel(const int* __restrict__ S,
                             const int* __restrict__ BS,
                             const int* __restrict__ deg,
                             int* __restrict__ rowptr,
                             float* __restrict__ dinv, int n) {
  int i = blockIdx.x * blockDim.x + threadIdx.x;
  if (i < n) {
    int d = deg[i];
    int r = S[i] + BS[i >> 10];      // inclusive prefix = rowptr[i+1]
    rowptr[i + 1] = r;
    dinv[i] = rsqrtf((float)d + 1.0f);
    if (i == 0) rowptr[0] = 0;
  }
}

// ---- fused: blocks [0,FILL_BLOCKS) do atomic-free CSR fill;
//      blocks [FILL_BLOCKS,...) do y' = dinv * (x @ W1) ----
#define XS_LD 68   // 64 + 4: float4-aligned, banks spread
#define FILL_BLOCKS 1024
__global__ __launch_bounds__(256) void fused_fill_gemm1_kernel(
    const int* __restrict__ eidx, int E, const int* __restrict__ rowptr,
    const int* __restrict__ pos, int* __restrict__ csr,
    const float* __restrict__ x, const float* __restrict__ W1,
    const float* __restrict__ dinv, float* __restrict__ y, int n) {
  __shared__ float xs[64 * XS_LD];    // 17.4 KiB
  __shared__ float wsh[64 * HID_C];   // 16 KiB, [k][j]
  int t = threadIdx.x;
  if ((int)blockIdx.x < FILL_BLOCKS) {
    // ---- CSR fill, no atomics: csr[rowptr[d] + pos[e]] = s ----
    int base = blockIdx.x * 256 + t;
    int stride = FILL_BLOCKS * 256;
    for (int e = base; e < E; e += 4 * stride) {
      int e1 = e + stride, e2 = e + 2 * stride, e3 = e + 3 * stride;
      bool g1 = e1 < E, g2 = e2 < E, g3 = e3 < E;
      int s0 = eidx[e], d0 = eidx[E + e], p0 = pos[e];
      int s1 = 0, d1 = 0, p1 = 0, s2 = 0, d2 = 0, p2 = 0, s3 = 0, d3 = 0, p3 = 0;
      if (g1) { s1 = eidx[e1]; d1 = eidx[E + e1]; p1 = pos[e1]; }
      if (g2) { s2 = eidx[e2]; d2 = eidx[E + e2]; p2 = pos[e2]; }
      if (g3) { s3 = eidx[e3]; d3 = eidx[E + e3]; p3 = pos[e3]; }
      int r0 = rowptr[d0];
      int r1 = g1 ? rowptr[d1] : 0;
      int r2 = g2 ? rowptr[d2] : 0;
      int r3 = g3 ? rowptr[d3] : 0;
      csr[r0 + p0] = s0;
      if (g1) csr[r1 + p1] = s1;
      if (g2) csr[r2 + p2] = s2;
      if (g3) csr[r3 + p3] = s3;
    }
    return;
  }
  // ---- GEMM1: 64x64 tile, K chunked by 64, 4x4 reg tile ----
  int rowBase = ((int)blockIdx.x - FILL_BLOCKS) * 64;
  const float4* xf4 = (const float4*)x;
  const float4* wf4 = (const float4*)W1;
  int tx = t & 15, ty = t >> 4;
  int i0 = ty * 4, j0 = tx * 4;
  float acc[4][4];
#pragma unroll
  for (int r = 0; r < 4; ++r)
#pragma unroll
    for (int j = 0; j < 4; ++j) acc[r][j] = 0.f;

  for (int kc = 0; kc < 2; ++kc) {           // K chunks of 64
#pragma unroll
    for (int k = 0; k < 4; ++k) {
      int t4 = t + k * 256;                  // 0..1023
      int row = t4 >> 4, c4 = t4 & 15;
      int gr = rowBase + row;
      if (gr >= n) gr = n - 1;
      *(float4*)&xs[row * XS_LD + c4 * 4] = xf4[(size_t)gr * 32 + kc * 16 + c4];
      *(float4*)&wsh[row * HID_C + c4 * 4] = wf4[(size_t)(kc * 64 + row) * 16 + c4];
    }
    __syncthreads();
#pragma unroll 2
    for (int c4 = 0; c4 < 64; c4 += 4) {
      float4 xv[4], wv[4];
#pragma unroll
      for (int r = 0; r < 4; ++r)
        xv[r] = *(const float4*)&xs[(i0 + r) * XS_LD + c4];
#pragma unroll
      for (int cc = 0; cc < 4; ++cc)
        wv[cc] = *(const float4*)&wsh[(c4 + cc) * HID_C + j0];
#pragma unroll
      for (int r = 0; r < 4; ++r) {
#pragma unroll
        for (int cc = 0; cc < 4; ++cc) {
          float xr = (&xv[r].x)[cc];
          acc[r][0] = fmaf(xr, wv[cc].x, acc[r][0]);
          acc[r][1] = fmaf(xr, wv[cc].y, acc[r][1]);
          acc[r][2] = fmaf(xr, wv[cc].z, acc[r][2]);
          acc[r][3] = fmaf(xr, wv[cc].w, acc[r][3]);
        }
      }
    }
    __syncthreads();
  }
#pragma unroll
  for (int r = 0; r < 4; ++r) {
    int i = rowBase + i0 + r;
    if (i < n) {
      float di = dinv[i];
      float4 v = make_float4(di * acc[r][0], di * acc[r][1],
                             di * acc[r][2], di * acc[r][3]);
      *(float4*)&y[(size_t)i * HID_C + j0] = v;
    }
  }
}

// ---- gather1: h = relu(dinv[i] * Σ y'[s] + b1)  (y' = dinv*y, f32) ----
// wave = node; 4 groups of 16 lanes, each takes every 4th edge, float4 ch;
// next-node rowptr/dinv prefetched (software pipeline)
__global__ __launch_bounds__(256) void gather1_kernel(
    const float4* __restrict__ y4, const int* __restrict__ rowptr,
    const int* __restrict__ csr, const float* __restrict__ dinv,
    const float* __restrict__ b1, float* __restrict__ h, int n) {
  int lane = threadIdx.x & 63;
  int grp = lane >> 4;             // 0..3: edge sub-group
  int q = lane & 15;               // channel quad (4q..4q+3)
  float4 b1v = ((const float4*)b1)[q];
  int wid = (int)((blockIdx.x * blockDim.x + threadIdx.x) >> 6);
  int nw = (int)((gridDim.x * blockDim.x) >> 6);
  int ii = wid;
  int e0 = 0, e1 = 0; float di = 0.f;
  if (ii < n) { e0 = rowptr[ii]; e1 = rowptr[ii + 1]; di = dinv[ii]; }
  while (ii < n) {
    int nxt = ii + nw;
    int ne0 = 0, ne1 = 0; float ndi = 0.f;
    if (nxt < n) { ne0 = rowptr[nxt]; ne1 = rowptr[nxt + 1]; ndi = dinv[nxt]; }
    int i = __builtin_amdgcn_readfirstlane(ii);
    float4 acc = make_float4(0.f, 0.f, 0.f, 0.f);
    if (grp == 0) acc = y4[(size_t)i * 16 + q];       // self term y'[i]
    int e = e0 + grp, end = e1;
    for (; e + 4 < end; e += 8) {
      int s0 = csr[e], s1 = csr[e + 4];
      float4 v0 = y4[(size_t)s0 * 16 + q];
      float4 v1 = y4[(size_t)s1 * 16 + q];
      acc.x += v0.x + v1.x;
      acc.y += v0.y + v1.y;
      acc.z += v0.z + v1.z;
      acc.w += v0.w + v1.w;
    }
    for (; e < end; e += 4) {
      int s = csr[e];
      float4 v = y4[(size_t)s * 16 + q];
      acc.x += v.x; acc.y += v.y; acc.z += v.z; acc.w += v.w;
    }
    // combine groups (xor 16, xor 32)
    acc.x += __shfl_xor(acc.x, 16); acc.y += __shfl_xor(acc.y, 16);
    acc.z += __shfl_xor(acc.z, 16); acc.w += __shfl_xor(acc.w, 16);
    acc.x += __shfl_xor(acc.x, 32); acc.y += __shfl_xor(acc.y, 32);
    acc.z += __shfl_xor(acc.z, 32); acc.w += __shfl_xor(acc.w, 32);
    if (grp == 0) {
      float4 hv;
      hv.x = fmaf(di, acc.x, b1v.x); hv.x = hv.x > 0.f ? hv.x : 0.f;
      hv.y = fmaf(di, acc.y, b1v.y); hv.y = hv.y > 0.f ? hv.y : 0.f;
      hv.z = fmaf(di, acc.z, b1v.z); hv.z = hv.z > 0.f ? hv.z : 0.f;
      hv.w = fmaf(di, acc.w, b1v.w); hv.w = hv.w > 0.f ? hv.w : 0.f;
      *(float4*)&h[(size_t)i * HID_C + 4 * q] = hv;
    }
    ii = nxt; e0 = ne0; e1 = ne1; di = ndi;
  }
}

// ---- z' = dinv * (h @ W2): 64-node x 40-col tile, 4x4 reg tile ----
__global__ __launch_bounds__(256) void gemm2_kernel(
    const float* __restrict__ h, const float* __restrict__ W2,
    const float* __restrict__ dinv, float* __restrict__ z, int n) {
  __shared__ float hs[64 * XS_LD];      // 17.4 KiB
  __shared__ float w2s[64 * OUT_C + 32];  // 10.4 KiB (+pad for idle-lane reads)
  int t = threadIdx.x;
  int rowBase = blockIdx.x * 64;
  const float4* hf4 = (const float4*)h;
  const float4* wf4 = (const float4*)W2;
#pragma unroll
  for (int k = 0; k < 4; ++k) {
    int t4 = t + k * 256;
    int row = t4 >> 4, c4 = t4 & 15;
    int gr = rowBase + row;
    if (gr >= n) gr = n - 1;
    *(float4*)&hs[row * XS_LD + c4 * 4] = hf4[(size_t)gr * 16 + c4];
  }
  for (int t4 = t; t4 < 640; t4 += 256)
    *(float4*)&w2s[t4 * 4] = wf4[t4];
  __syncthreads();
  int tx = t & 15, ty = t >> 4;
  int i0 = ty * 4, j0 = tx * 4;
  bool active = tx < 10;               // 40 cols = 10 quads
  float acc[4][4];
#pragma unroll
  for (int r = 0; r < 4; ++r)
#pragma unroll
    for (int j = 0; j < 4; ++j) acc[r][j] = 0.f;
#pragma unroll 2
  for (int c4 = 0; c4 < 64; c4 += 4) {
    float4 hv[4], wv[4];
#pragma unroll
    for (int r = 0; r < 4; ++r)
      hv[r] = *(const float4*)&hs[(i0 + r) * XS_LD + c4];
#pragma unroll
    for (int cc = 0; cc < 4; ++cc)
      wv[cc] = *(const float4*)&w2s[(c4 + cc) * OUT_C + j0];
#pragma unroll
    for (int r = 0; r < 4; ++r) {
#pragma unroll
      for (int cc = 0; cc < 4; ++cc) {
        float hr = (&hv[r].x)[cc];
        acc[r][0] = fmaf(hr, wv[cc].x, acc[r][0]);
        acc[r][1] = fmaf(hr, wv[cc].y, acc[r][1]);
        acc[r][2] = fmaf(hr, wv[cc].z, acc[r][2]);
        acc[r][3] = fmaf(hr, wv[cc].w, acc[r][3]);
      }
    }
  }
  if (active) {
#pragma unroll
    for (int r = 0; r < 4; ++r) {
      int i = rowBase + i0 + r;
      if (i < n) {
        float di = dinv[i];
        float4 v = make_float4(di * acc[r][0], di * acc[r][1],
                               di * acc[r][2], di * acc[r][3]);
        *(float4*)&z[(size_t)i * OUT_C + j0] = v;
      }
    }
  }
}

// ---- gather(z') + bias + log-softmax: 4 groups, q<10 active, prefetch ----
__global__ __launch_bounds__(256) void gather40_kernel(
    const float4* __restrict__ z4, const int* __restrict__ rowptr,
    const int* __restrict__ csr, const float* __restrict__ dinv,
    const float* __restrict__ b2, float* __restrict__ out, int n) {
  int lane = threadIdx.x & 63;
  int grp = lane >> 4;             // 0..3: edge sub-group
  int q = lane & 15;               // channel quad; active q<10 (40 ch)
  bool act = q < 10;
  float4 b2v = ((const float4*)b2)[act ? q : 0];
  int wid = (int)((blockIdx.x * blockDim.x + threadIdx.x) >> 6);
  int nw = (int)((gridDim.x * blockDim.x) >> 6);
  int ii = wid;
  int e0 = 0, e1 = 0; float di = 0.f;
  if (ii < n) { e0 = rowptr[ii]; e1 = rowptr[ii + 1]; di = dinv[ii]; }
  while (ii < n) {
    int nxt = ii + nw;
    int ne0 = 0, ne1 = 0; float ndi = 0.f;
    if (nxt < n) { ne0 = rowptr[nxt]; ne1 = rowptr[nxt + 1]; ndi = dinv[nxt]; }
    int i = __builtin_amdgcn_readfirstlane(ii);
    float4 acc = make_float4(0.f, 0.f, 0.f, 0.f);
    if (grp == 0 && act) acc = z4[(size_t)i * 10 + q];    // self term z'[i]
    int e = e0 + grp, end = e1;
    if (act) {
      for (; e + 4 < end; e += 8) {
        int s0 = csr[e], s1 = csr[e + 4];
        float4 v0 = z4[(size_t)s0 * 10 + q];
        float4 v1 = z4[(size_t)s1 * 10 + q];
        acc.x += v0.x + v1.x;
        acc.y += v0.y + v1.y;
        acc.z += v0.z + v1.z;
        acc.w += v0.w + v1.w;
      }
      for (; e < end; e += 4) {
        int s = csr[e];
        float4 v = z4[(size_t)s * 10 + q];
        acc.x += v.x; acc.y += v.y; acc.z += v.z; acc.w += v.w;
      }
    }
    // combine groups (inactive lanes hold zeros everywhere)
    acc.x += __shfl_xor(acc.x, 16); acc.y += __shfl_xor(acc.y, 16);
    acc.z += __shfl_xor(acc.z, 16); acc.w += __shfl_xor(acc.w, 16);
    acc.x += __shfl_xor(acc.x, 32); acc.y += __shfl_xor(acc.y, 32);
    acc.z += __shfl_xor(acc.z, 32); acc.w += __shfl_xor(acc.w, 32);
    float4 o;
    o.x = fmaf(di, acc.x, b2v.x);
    o.y = fmaf(di, acc.y, b2v.y);
    o.z = fmaf(di, acc.z, b2v.z);
    o.w = fmaf(di, acc.w, b2v.w);
    // max over 40 ch: per-lane max4, butterfly within 16-lane group
    float m = act ? fmaxf(fmaxf(o.x, o.y), fmaxf(o.z, o.w)) : -INFINITY;
    for (int off = 8; off; off >>= 1) m = fmaxf(m, __shfl_xor(m, off));
    float ex = act ? (expf(o.x - m) + expf(o.y - m) +
                      expf(o.z - m) + expf(o.w - m)) : 0.f;
    float s = ex;
    for (int off = 8; off; off >>= 1) s += __shfl_xor(s, off);
    if (lane < 16 && act) {       // group 0 stores, float4 per lane
      float l = m + logf(s);
      float4 o2 = make_float4(o.x - l, o.y - l, o.z - l, o.w - l);
      *(float4*)&out[(size_t)i * OUT_C + 4 * q] = o2;
    }
    ii = nxt; e0 = ne0; e1 = ne1; di = ndi;
  }
}

extern "C" void kernel_launch(void* const* d_in, const int* in_sizes, int n_in,
                              void* d_out, int out_size, void* d_ws, size_t ws_size,
                              hipStream_t stream) {
  const float* x  = (const float*)d_in[0];
  const int* eidx = (const int*)d_in[1];   // harness delivers integers as int32
  const float* W1 = (const float*)d_in[2];
  const float* b1 = (const float*)d_in[3];
  const float* W2 = (const float*)d_in[4];
  const float* b2 = (const float*)d_in[5];
  float* out = (float*)d_out;

  int n = in_sizes[0] / IN_C;
  int E = in_sizes[1] / 2;

  size_t npad = ((size_t)n + 255) & ~(size_t)255;
  size_t Epad = ((size_t)E + 255) & ~(size_t)255;
  // layout (4-byte units)
  size_t o_dinv   = 0;
  size_t o_deg    = o_dinv + npad;
  size_t o_S      = o_deg + npad;
  size_t o_BS     = o_S + npad;
  size_t o_rowptr = o_BS + 256;
  size_t o_pos    = o_rowptr + npad + 256;
  size_t o_csr    = o_pos + Epad;
  size_t o_bufA   = o_csr + Epad;                 // y' then z' (n x 64 f32)
  size_t o_bufC   = o_bufA + (size_t)n * HID_C;   // h (n x 64 f32)
  size_t needed   = (o_bufC + (size_t)n * HID_C) * 4;
  if (ws_size < needed) return;  // fail via absmax, not GPU fault

  float* ws  = (float*)d_ws;
  float* dinv = ws + o_dinv;
  int* deg    = (int*)(ws + o_deg);
  int* S      = (int*)(ws + o_S);
  int* BS     = (int*)(ws + o_BS);
  int* rowptr = (int*)(ws + o_rowptr);
  int* pos    = (int*)(ws + o_pos);
  int* csr    = (int*)(ws + o_csr);
  float* bufA = ws + o_bufA;   // y' (n x 64) -> z' (n x 40)
  float* bufC = ws + o_bufC;   // h (n x 64)

  int nb = (int)((n + 1023) / 1024);   // 98 for n=100k; scan2 supports <=128

  // ---- CSR build prefix: deg+pos, scan, rowptr+dinv ----
  zero4_kernel<<<128, 256, 0, stream>>>((int4*)deg, (long long)(npad / 4));
  degpos_kernel<<<1024, 256, 0, stream>>>(eidx + E, E, deg, pos);
  scan1_kernel<<<nb, 256, 0, stream>>>(deg, S, BS, n);
  scan2_kernel<<<1, 128, 0, stream>>>(BS, nb);
  scan3_kernel<<<(n + 255) / 256, 256, 0, stream>>>(S, BS, deg, rowptr, dinv, n);

  // ---- fused: atomic-free CSR fill || y' = dinv * (x @ W1) ----
  int gemmBlocks = (n + 63) / 64;
  fused_fill_gemm1_kernel<<<FILL_BLOCKS + gemmBlocks, 256, 0, stream>>>(
      eidx, E, rowptr, pos, csr, x, W1, dinv, bufA, n);

  // ---- layer 1 gather: h = relu(dinv_i * sum(y'_s) + b1) ----
  gather1_kernel<<<2048, 256, 0, stream>>>((const float4*)bufA, rowptr, csr,
                                           dinv, b1, bufC, n);
  // ---- layer 2: z' = dinv*(h@W2) ; out = logsoftmax(dinv*gather(z')+b2) ----
  gemm2_kernel<<<(n + 63) / 64, 256, 0, stream>>>(bufC, W2, dinv, bufA, n);
  gather40_kernel<<<2048, 256, 0, stream>>>((const float4*)bufA, rowptr, csr,
                                            dinv, b2, out, n);
}